// Round 9
// baseline (1404.188 us; speedup 1.0000x reference)
//
#include <hip/hip_runtime.h>
#include <stdint.h>

#define EPS 1e-5f

typedef __attribute__((ext_vector_type(4))) int i32x4;

// ---------------------------------------------------------------------------
// conv1 -> a1: fp32 conv 3->384 + BN + sign, output i8 +-1 into padded NHWC
// a1[n][y+1][x+1][co], borders pre-zeroed by memset.
// ---------------------------------------------------------------------------
__global__ void conv1_a1_kernel(const float* __restrict__ x,
                                const float* __restrict__ w1,
                                const float* __restrict__ g,
                                const float* __restrict__ b,
                                const float* __restrict__ m,
                                const float* __restrict__ v,
                                char* __restrict__ a1)
{
    int bid = blockIdx.x;
    int n = bid >> 5;
    int y = bid & 31;
    int tid = threadIdx.x;
    int xo = tid & 31;
    int cog = tid >> 5;   // 0..11

    float a[27];
#pragma unroll
    for (int ci = 0; ci < 3; ++ci)
#pragma unroll
        for (int dy = 0; dy < 3; ++dy)
#pragma unroll
            for (int dx = 0; dx < 3; ++dx) {
                int yy = y + dy - 1, xx = xo + dx - 1;
                float val = 0.f;
                if (yy >= 0 && yy < 32 && xx >= 0 && xx < 32)
                    val = x[((n * 3 + ci) * 32 + yy) * 32 + xx];
                a[(ci * 3 + dy) * 3 + dx] = val;
            }

    uint32_t w4[8];
#pragma unroll
    for (int i = 0; i < 8; ++i) w4[i] = 0;
    for (int cs = 0; cs < 32; ++cs) {
        int co = cog * 32 + cs;
        const float* wp = w1 + co * 27;
        float acc = 0.f;
#pragma unroll
        for (int i = 0; i < 27; ++i) acc += a[i] * wp[i];
        float t = (acc - m[co]) * (g[co] * rsqrtf(v[co] + EPS)) + b[co];
        uint32_t byte = (t >= 0.f) ? 0x01u : 0xFFu;
        w4[cs >> 2] |= byte << (8 * (cs & 3));
    }
    char* dst = a1 + (((size_t)(n * 34 + y + 1) * 34 + (xo + 1)) * 384 + cog * 32);
    ((uint4*)dst)[0] = make_uint4(w4[0], w4[1], w4[2], w4[3]);
    ((uint4*)dst)[1] = make_uint4(w4[4], w4[5], w4[6], w4[7]);
}

// ---------------------------------------------------------------------------
// B repack into fragment order: Bp[s][col][fg*16+t], s = tap*KC+kc,
// element = sign(w[col][ci=kc*64+fg*16+t][tap]).  Padded by one chunk for
// branchless rolling prefetch.
// ---------------------------------------------------------------------------
__global__ void pack_bp_kernel(const float* __restrict__ w,
                               char* __restrict__ bp, int Co, int Ci)
{
    int KC = Ci >> 6;
    int idx = blockIdx.x * 256 + threadIdx.x;
    int total = Co * 9 * Ci;
    if (idx >= total) return;
    int t  = idx & 15;
    int fg = (idx >> 4) & 3;
    int co = (idx >> 6) % Co;
    int s  = idx / (Co * 64);
    int tap = s / KC, kc = s % KC;
    int ci = kc * 64 + fg * 16 + t;
    bp[idx] = (w[((size_t)co * Ci + ci) * 9 + tap] >= 0.f) ? 1 : -1;
}

// ---------------------------------------------------------------------------
// gemm_db: double-buffered implicit-GEMM binary conv (i8 MFMA).
// M-tile 128 (pixels), N-tile 128 (cout), K-step 128 (two 64B chunks per
// barrier: R7 post-mortem showed 2-phase tax ~2700 cyc/step vs 1305 cyc of
// MFMA -> double MFMA per barrier, halve barrier count).
// LDS [2][128 rows x 128B]; swizzle: 16B physical slot = logical ^ (row&7)
// on BOTH write and read -> every b128 op is 2-way (free, m136).
// Grid: 1D, bijective XCD chunking (bm-stripe per XCD, bn fastest) - kept
// from R7 (FETCH 621->60MB verified).
// B: registers, rolling one-chunk-ahead prefetch from padded Bp.
// 4 waves (2x2), wave tile 64x64; 32 MFMA/wave/barrier.
// ---------------------------------------------------------------------------
template<int Ci, int Co, int H, int W, int GN>
__global__ __launch_bounds__(256, 4) void gemm_db_kernel(
    const char* __restrict__ A,
    const char* __restrict__ Bp,
    short* __restrict__ Cc)
{
    constexpr int KC  = Ci / 64;        // 64B chunks per tap (even for all)
    constexpr int S   = 9 * KC;         // total chunks
    constexpr int NIT = S / 2;          // iterations (K=128 each)
    constexpr int JP  = KC / 2;         // 128B segments per tap
    constexpr int WP  = W + 2;
    constexpr int GM  = (128 * H * W) / 128;

    __shared__ __align__(16) char lds[2][128 * 128];

    const int id = blockIdx.x;
    const int xcd = id & 7;
    const int s0 = id >> 3;
    const int bm = xcd * (GM / 8) + s0 / GN;
    const int bn = s0 % GN;

    const int tid = threadIdx.x;
    const int lane = tid & 63;
    const int wave = tid >> 6;
    const int wm = wave >> 1, wn = wave & 1;
    const int fr = lane & 15, fg = lane >> 4;

    // staging role: row pl (0..127), half h (0..1) -> 64B contiguous each
    const int pl = tid >> 1, h = tid & 1;
    int gm = bm * 128 + pl;
    int n  = gm / (H * W);
    int rr = gm % (H * W);
    int y  = rr / W, x = rr % W;
    const char* abase = A + ((size_t)(n * (H + 2) + y) * WP + x) * Ci + h * 64;

    // physical write offsets: logical slots h*4+k, phys = slot ^ (pl&7)
    int wso[4];
#pragma unroll
    for (int k = 0; k < 4; ++k)
        wso[k] = pl * 128 + (((h * 4 + k) ^ (pl & 7)) << 4);

    // read offsets per chunk c (0/1): logical slot c*4+fg, phys ^ (row&7)
    int ra0[4], ra1[4];
#pragma unroll
    for (int i = 0; i < 4; ++i) {
        int row = wm * 64 + i * 16 + fr;
        ra0[i] = row * 128 + (((fg) ^ (row & 7)) << 4);
        ra1[i] = row * 128 + (((4 + fg) ^ (row & 7)) << 4);
    }

    size_t boff[4];
#pragma unroll
    for (int j = 0; j < 4; ++j) {
        int col = bn * 128 + wn * 64 + j * 16 + fr;
        boff[j] = (size_t)col * 64 + (size_t)fg * 16;
    }
    const size_t bstep = (size_t)Co * 64;

    i32x4 acc[4][4] = {};

    // prologue: stage iteration 0 (tap 0, j 0), load B chunk 0
    {
        const char* src = abase;
#pragma unroll
        for (int k = 0; k < 4; ++k)
            *reinterpret_cast<uint4*>(&lds[0][wso[k]]) =
                *reinterpret_cast<const uint4*>(src + k * 16);
    }
    i32x4 bf[4];
#pragma unroll
    for (int j = 0; j < 4; ++j)
        bf[j] = *reinterpret_cast<const i32x4*>(Bp + boff[j]);
    __syncthreads();

    for (int it = 0; it < NIT; ++it) {
        const int cur = it & 1;
        const bool more = (it + 1 < NIT);

        // A prefetch for next iteration (contiguous 64B)
        uint4 avn[4];
        if (more) {
            int it1 = it + 1;
            int tap = it1 / JP, j = it1 % JP;
            const char* src = abase + ((tap / 3) * WP + (tap % 3)) * Ci + j * 128;
#pragma unroll
            for (int k = 0; k < 4; ++k)
                avn[k] = *reinterpret_cast<const uint4*>(src + k * 16);
        }

        // ---- chunk 0 (s = 2it): prefetch B(2it+1), MFMA on bf ----
        i32x4 bfn[4];
#pragma unroll
        for (int j = 0; j < 4; ++j)
            bfn[j] = *reinterpret_cast<const i32x4*>(
                Bp + (size_t)(2 * it + 1) * bstep + boff[j]);
        {
            i32x4 af[4];
#pragma unroll
            for (int i = 0; i < 4; ++i)
                af[i] = *reinterpret_cast<const i32x4*>(&lds[cur][ra0[i]]);
#pragma unroll
            for (int i = 0; i < 4; ++i)
#pragma unroll
                for (int j = 0; j < 4; ++j)
                    acc[i][j] = __builtin_amdgcn_mfma_i32_16x16x64_i8(
                        af[i], bf[j], acc[i][j], 0, 0, 0);
        }

        // ---- chunk 1 (s = 2it+1): prefetch B(2it+2), MFMA on bfn ----
        i32x4 bf2[4];
#pragma unroll
        for (int j = 0; j < 4; ++j)
            bf2[j] = *reinterpret_cast<const i32x4*>(
                Bp + (size_t)(2 * it + 2) * bstep + boff[j]);
        {
            i32x4 af[4];
#pragma unroll
            for (int i = 0; i < 4; ++i)
                af[i] = *reinterpret_cast<const i32x4*>(&lds[cur][ra1[i]]);
#pragma unroll
            for (int i = 0; i < 4; ++i)
#pragma unroll
                for (int j = 0; j < 4; ++j)
                    acc[i][j] = __builtin_amdgcn_mfma_i32_16x16x64_i8(
                        af[i], bfn[j], acc[i][j], 0, 0, 0);
        }

        if (more) {
#pragma unroll
            for (int k = 0; k < 4; ++k)
                *reinterpret_cast<uint4*>(&lds[cur ^ 1][wso[k]]) = avn[k];
        }
#pragma unroll
        for (int j = 0; j < 4; ++j) bf[j] = bf2[j];
        __syncthreads();
    }

    // epilogue: frag row = i*16 + fg*4 + r, col = j*16 + fr (verified map)
#pragma unroll
    for (int i = 0; i < 4; ++i) {
#pragma unroll
        for (int r = 0; r < 4; ++r) {
            int p = bm * 128 + wm * 64 + i * 16 + fg * 4 + r;
            int nn = p / (H * W);
            int r2 = p % (H * W);
            size_t crow = ((size_t)(nn * H + r2 / W) * W + r2 % W) * Co;
#pragma unroll
            for (int j = 0; j < 4; ++j) {
                int col = bn * 128 + wn * 64 + j * 16 + fr;
                Cc[crow + col] = (short)acc[i][j][r];
            }
        }
    }
}

// ---------------------------------------------------------------------------
// pool(optional 2x2) + BN + sign -> i8 +-1 padded NHWC for next layer
// ---------------------------------------------------------------------------
__global__ void pool_sign_kernel(const short* __restrict__ c,
                                 const float* __restrict__ g,
                                 const float* __restrict__ b,
                                 const float* __restrict__ m,
                                 const float* __restrict__ v,
                                 char* __restrict__ outp,
                                 int H, int W, int Ho, int Wo, int Co,
                                 int pool, int total)
{
    int idx = blockIdx.x * 256 + threadIdx.x;
    if (idx >= total) return;
    int co = idx % Co;
    int t  = idx / Co;
    int xo = t % Wo; t /= Wo;
    int yo = t % Ho;
    int n  = t / Ho;
    int best;
    if (pool) {
        int m00 = c[((size_t)((n * H + 2 * yo) * W + 2 * xo)) * Co + co];
        int m01 = c[((size_t)((n * H + 2 * yo) * W + 2 * xo + 1)) * Co + co];
        int m10 = c[((size_t)((n * H + 2 * yo + 1) * W + 2 * xo)) * Co + co];
        int m11 = c[((size_t)((n * H + 2 * yo + 1) * W + 2 * xo + 1)) * Co + co];
        best = max(max(m00, m01), max(m10, m11));
    } else {
        best = c[((size_t)((n * H + yo) * W + xo)) * Co + co];
    }
    float tt = ((float)best - m[co]) * (g[co] * rsqrtf(v[co] + EPS)) + b[co];
    outp[((size_t)(n * (Ho + 2) + yo + 1) * (Wo + 2) + xo + 1) * Co + co] =
        tt >= 0.f ? 1 : -1;
}

// ---------------------------------------------------------------------------
// final: pool 2x2 + BN + hardtanh -> fp32 NCHW h6[n][co][yo][xo] (4x4)
// ---------------------------------------------------------------------------
__global__ void pool6_ht_kernel(const short* __restrict__ c,
                                const float* __restrict__ g,
                                const float* __restrict__ b,
                                const float* __restrict__ m,
                                const float* __restrict__ v,
                                float* __restrict__ h6)
{
    int idx = blockIdx.x * 256 + threadIdx.x;
    if (idx >= 128 * 512 * 16) return;
    int xo = idx & 3;
    int yo = (idx >> 2) & 3;
    int t  = idx >> 4;
    int co = t % 512;
    int n  = t / 512;
    int m00 = c[((size_t)((n * 8 + 2 * yo) * 8 + 2 * xo)) * 512 + co];
    int m01 = c[((size_t)((n * 8 + 2 * yo) * 8 + 2 * xo + 1)) * 512 + co];
    int m10 = c[((size_t)((n * 8 + 2 * yo + 1) * 8 + 2 * xo)) * 512 + co];
    int m11 = c[((size_t)((n * 8 + 2 * yo + 1) * 8 + 2 * xo + 1)) * 512 + co];
    int best = max(max(m00, m01), max(m10, m11));
    float tt = ((float)best - m[co]) * (g[co] * rsqrtf(v[co] + EPS)) + b[co];
    tt = fminf(1.f, fmaxf(-1.f, tt));
    h6[((size_t)(n * 512 + co) * 4 + yo) * 4 + xo] = tt;
}

// ---------------------------------------------------------------------------
// classifier: logits = h @ w_lin.T (128 x 8192 x 10) then log_softmax
// ---------------------------------------------------------------------------
__global__ void classifier_kernel(const float* __restrict__ h,
                                  const float* __restrict__ wl,
                                  float* __restrict__ out)
{
    int n = blockIdx.x;
    int tid = threadIdx.x;
    float acc[10];
#pragma unroll
    for (int j = 0; j < 10; ++j) acc[j] = 0.f;
    for (int k = tid; k < 8192; k += 256) {
        float hv = h[n * 8192 + k];
#pragma unroll
        for (int j = 0; j < 10; ++j) acc[j] += hv * wl[j * 8192 + k];
    }
    __shared__ float sred[256];
    __shared__ float logit[10];
    for (int j = 0; j < 10; ++j) {
        sred[tid] = acc[j];
        __syncthreads();
        for (int s = 128; s > 0; s >>= 1) {
            if (tid < s) sred[tid] += sred[tid + s];
            __syncthreads();
        }
        if (tid == 0) logit[j] = sred[0];
        __syncthreads();
    }
    if (tid == 0) {
        float mx = logit[0];
#pragma unroll
        for (int j = 1; j < 10; ++j) mx = fmaxf(mx, logit[j]);
        float s = 0.f;
#pragma unroll
        for (int j = 0; j < 10; ++j) s += expf(logit[j] - mx);
        float lse = logf(s) + mx;
#pragma unroll
        for (int j = 0; j < 10; ++j) out[n * 10 + j] = logit[j] - lse;
    }
}

// ===========================================================================
extern "C" void kernel_launch(void* const* d_in, const int* in_sizes, int n_in,
                              void* d_out, int out_size, void* d_ws, size_t ws_size,
                              hipStream_t stream)
{
    const float* x    = (const float*)d_in[0];
    const float* w1   = (const float*)d_in[1];
    const float* w2   = (const float*)d_in[2];
    const float* w3   = (const float*)d_in[3];
    const float* w4   = (const float*)d_in[4];
    const float* w5   = (const float*)d_in[5];
    const float* w6   = (const float*)d_in[6];
    const float* bn_g[6], *bn_b[6], *bn_m[6], *bn_v[6];
    for (int i = 0; i < 6; ++i) {
        bn_g[i] = (const float*)d_in[7 + i * 4 + 0];
        bn_b[i] = (const float*)d_in[7 + i * 4 + 1];
        bn_m[i] = (const float*)d_in[7 + i * 4 + 2];
        bn_v[i] = (const float*)d_in[7 + i * 4 + 3];
    }
    const float* wlin = (const float*)d_in[31];
    float* out = (float*)d_out;

    // rotating activation/conv-out slots (R4-R8-verified liveness plan)
    const size_t A1 = (size_t)128 * 34 * 34 * 384;     // 56.8 MB
    const size_t A2 = (size_t)128 * 18 * 18 * 384;
    const size_t A3 = (size_t)128 * 18 * 18 * 768;
    const size_t A4 = (size_t)128 * 10 * 10 * 768;
    const size_t A5 = (size_t)128 * 10 * 10 * 1536;
    const size_t C2 = (size_t)131072 * 384 * 2;        // 100.7 MB
    const size_t C4 = (size_t)32768 * 768 * 2;         // 50.3 MB
    const size_t S0 = A1;                              // holds a1,c3,a4,c6
    const size_t S1 = C2;                              // holds c2,a3,c5,h6
    const size_t S2 = C4;                              // holds a2,c4,a5

    char* ws = (char*)d_ws;
    auto alloc = [&](size_t bytes) {
        char* p = ws;
        ws += (bytes + 255) & ~(size_t)255;
        return p;
    };
    char* s0 = (char*)alloc(S0);
    char* s1 = (char*)alloc(S1);
    char* s2 = (char*)alloc(S2);
    // B packs, padded by one chunk (branchless rolling prefetch)
    char* bp2 = (char*)alloc((size_t)(9 * 6 + 1) * 384 * 64);
    char* bp3 = (char*)alloc((size_t)(9 * 6 + 1) * 768 * 64);
    char* bp4 = (char*)alloc((size_t)(9 * 12 + 1) * 768 * 64);
    char* bp5 = (char*)alloc((size_t)(9 * 12 + 1) * 1536 * 64);
    char* bp6 = (char*)alloc((size_t)(9 * 24 + 1) * 512 * 64);

    char*  a1 = s0;
    short* c2 = (short*)s1;
    char*  a2 = s2;
    short* c3 = (short*)s0;
    char*  a3 = s1;
    short* c4 = (short*)s2;
    char*  a4 = s0;
    short* c5 = (short*)s1;
    char*  a5 = s2;
    short* c6 = (short*)s0;
    float* h6 = (float*)s1;

    // B repacks
    {
        int t;
        t = 384 * 9 * 384;
        pack_bp_kernel<<<(t + 255) / 256, 256, 0, stream>>>(w2, bp2, 384, 384);
        t = 768 * 9 * 384;
        pack_bp_kernel<<<(t + 255) / 256, 256, 0, stream>>>(w3, bp3, 768, 384);
        t = 768 * 9 * 768;
        pack_bp_kernel<<<(t + 255) / 256, 256, 0, stream>>>(w4, bp4, 768, 768);
        t = 1536 * 9 * 768;
        pack_bp_kernel<<<(t + 255) / 256, 256, 0, stream>>>(w5, bp5, 1536, 768);
        t = 512 * 9 * 1536;
        pack_bp_kernel<<<(t + 255) / 256, 256, 0, stream>>>(w6, bp6, 512, 1536);
    }

    // block 1 -> a1 (padded i8)
    hipMemsetAsync(a1, 0, A1, stream);
    conv1_a1_kernel<<<128 * 32, 384, 0, stream>>>(
        x, w1, bn_g[0], bn_b[0], bn_m[0], bn_v[0], a1);

    // L2: 384->384 @32x32   GM=1024, GN=3
    gemm_db_kernel<384, 384, 32, 32, 3><<<1024 * 3, 256, 0, stream>>>(a1, bp2, c2);
    hipMemsetAsync(a2, 0, A2, stream);
    {
        int total = 128 * 16 * 16 * 384;
        pool_sign_kernel<<<(total + 255) / 256, 256, 0, stream>>>(
            c2, bn_g[1], bn_b[1], bn_m[1], bn_v[1], a2, 32, 32, 16, 16, 384, 1, total);
    }
    // L3: 384->768 @16x16   GM=256, GN=6
    gemm_db_kernel<384, 768, 16, 16, 6><<<256 * 6, 256, 0, stream>>>(a2, bp3, c3);
    hipMemsetAsync(a3, 0, A3, stream);
    {
        int total = 128 * 16 * 16 * 768;
        pool_sign_kernel<<<(total + 255) / 256, 256, 0, stream>>>(
            c3, bn_g[2], bn_b[2], bn_m[2], bn_v[2], a3, 16, 16, 16, 16, 768, 0, total);
    }
    // L4: 768->768 @16x16   GM=256, GN=6
    gemm_db_kernel<768, 768, 16, 16, 6><<<256 * 6, 256, 0, stream>>>(a3, bp4, c4);
    hipMemsetAsync(a4, 0, A4, stream);
    {
        int total = 128 * 8 * 8 * 768;
        pool_sign_kernel<<<(total + 255) / 256, 256, 0, stream>>>(
            c4, bn_g[3], bn_b[3], bn_m[3], bn_v[3], a4, 16, 16, 8, 8, 768, 1, total);
    }
    // L5: 768->1536 @8x8    GM=64, GN=12
    gemm_db_kernel<768, 1536, 8, 8, 12><<<64 * 12, 256, 0, stream>>>(a4, bp5, c5);
    hipMemsetAsync(a5, 0, A5, stream);
    {
        int total = 128 * 8 * 8 * 1536;
        pool_sign_kernel<<<(total + 255) / 256, 256, 0, stream>>>(
            c5, bn_g[4], bn_b[4], bn_m[4], bn_v[4], a5, 8, 8, 8, 8, 1536, 0, total);
    }
    // L6: 1536->512 @8x8    GM=64, GN=4
    gemm_db_kernel<1536, 512, 8, 8, 4><<<64 * 4, 256, 0, stream>>>(a5, bp6, c6);
    {
        int total = 128 * 512 * 16;
        pool6_ht_kernel<<<(total + 255) / 256, 256, 0, stream>>>(
            c6, bn_g[5], bn_b[5], bn_m[5], bn_v[5], h6);
    }
    classifier_kernel<<<128, 256, 0, stream>>>(h6, wlin, out);
}

// Round 10
// 1186.448 us; speedup vs baseline: 1.1835x; 1.1835x over previous
//
#include <hip/hip_runtime.h>
#include <stdint.h>

#define EPS 1e-5f

typedef __attribute__((ext_vector_type(4))) int i32x4;

// ---------------------------------------------------------------------------
// conv1 -> a1: fp32 conv 3->384 + BN + sign, output i8 +-1 into padded NHWC
// a1[n][y+1][x+1][co], borders pre-zeroed by memset.
// ---------------------------------------------------------------------------
__global__ void conv1_a1_kernel(const float* __restrict__ x,
                                const float* __restrict__ w1,
                                const float* __restrict__ g,
                                const float* __restrict__ b,
                                const float* __restrict__ m,
                                const float* __restrict__ v,
                                char* __restrict__ a1)
{
    int bid = blockIdx.x;
    int n = bid >> 5;
    int y = bid & 31;
    int tid = threadIdx.x;
    int xo = tid & 31;
    int cog = tid >> 5;   // 0..11

    float a[27];
#pragma unroll
    for (int ci = 0; ci < 3; ++ci)
#pragma unroll
        for (int dy = 0; dy < 3; ++dy)
#pragma unroll
            for (int dx = 0; dx < 3; ++dx) {
                int yy = y + dy - 1, xx = xo + dx - 1;
                float val = 0.f;
                if (yy >= 0 && yy < 32 && xx >= 0 && xx < 32)
                    val = x[((n * 3 + ci) * 32 + yy) * 32 + xx];
                a[(ci * 3 + dy) * 3 + dx] = val;
            }

    uint32_t w4[8];
#pragma unroll
    for (int i = 0; i < 8; ++i) w4[i] = 0;
    for (int cs = 0; cs < 32; ++cs) {
        int co = cog * 32 + cs;
        const float* wp = w1 + co * 27;
        float acc = 0.f;
#pragma unroll
        for (int i = 0; i < 27; ++i) acc += a[i] * wp[i];
        float t = (acc - m[co]) * (g[co] * rsqrtf(v[co] + EPS)) + b[co];
        uint32_t byte = (t >= 0.f) ? 0x01u : 0xFFu;
        w4[cs >> 2] |= byte << (8 * (cs & 3));
    }
    char* dst = a1 + (((size_t)(n * 34 + y + 1) * 34 + (xo + 1)) * 384 + cog * 32);
    ((uint4*)dst)[0] = make_uint4(w4[0], w4[1], w4[2], w4[3]);
    ((uint4*)dst)[1] = make_uint4(w4[4], w4[5], w4[6], w4[7]);
}

// ---------------------------------------------------------------------------
// B repack into fragment order: Bp[s][col][fg*16+t], s = tap*KC+kc,
// element = sign(w[col][ci=kc*64+fg*16+t][tap]).  Padded by one chunk for
// branchless prefetch.
// ---------------------------------------------------------------------------
__global__ void pack_bp_kernel(const float* __restrict__ w,
                               char* __restrict__ bp, int Co, int Ci)
{
    int KC = Ci >> 6;
    int idx = blockIdx.x * 256 + threadIdx.x;
    int total = Co * 9 * Ci;
    if (idx >= total) return;
    int t  = idx & 15;
    int fg = (idx >> 4) & 3;
    int co = (idx >> 6) % Co;
    int s  = idx / (Co * 64);
    int tap = s / KC, kc = s % KC;
    int ci = kc * 64 + fg * 16 + t;
    bp[idx] = (w[((size_t)co * Ci + ci) * 9 + tap] >= 0.f) ? 1 : -1;
}

// ---------------------------------------------------------------------------
// gemm_lds: double-buffered implicit-GEMM binary conv (i8 MFMA), A AND B
// staged through LDS.
// R8 post-mortem: MfmaUtil pinned ~27% by per-CU vector-memory return BW --
// each wave loaded its own B frags from global (2x redundant per block).
// Now: M-tile = WM*64 (256 for big layers), N-tile 128, K-step 64;
// B staged once per block into LDS (8KB/chunk), read via swizzled
// ds_read_b128 (slot ^= (idx>>1)&3 on write AND read; R7-verified
// conflict-free at stride 64). Global bytes per block-iter: A TM*64 + B 8KB
// -> 2x fewer bytes/MFMA at WM=4.
// Waves: WM x 2, wave tile 64x64 (16 MFMA/iter). XCD-chunked 1D grid (R7).
// ---------------------------------------------------------------------------
template<int Ci, int Co, int H, int W, int WM, int GN>
__global__ __launch_bounds__(WM * 128, 4) void gemm_lds_kernel(
    const char* __restrict__ A,
    const char* __restrict__ Bp,
    short* __restrict__ Cc)
{
    constexpr int T   = WM * 128;        // threads
    constexpr int TM  = WM * 64;         // M tile
    constexpr int KC  = Ci / 64;
    constexpr int S   = 9 * KC;
    constexpr int WP  = W + 2;
    constexpr int GM  = (128 * H * W) / TM;
    constexpr int BU  = 512 / T;         // B 16B-units per thread (1 or 2)

    __shared__ __align__(16) char lsA[2][TM * 64];
    __shared__ __align__(16) char lsB[2][128 * 64];

    const int id = blockIdx.x;
    const int xcd = id & 7;
    const int s0 = id >> 3;
    const int bm = xcd * (GM / 8) + s0 / GN;
    const int bn = s0 % GN;

    const int tid = threadIdx.x;
    const int lane = tid & 63;
    const int wave = tid >> 6;
    const int wm = wave >> 1, wn = wave & 1;
    const int fr = lane & 15, fg = lane >> 4;

    // ---- A staging role: row pl, half h (32B each) ----
    const int pl = tid >> 1, h = tid & 1;
    int gm = bm * TM + pl;
    int n  = gm / (H * W);
    int rr = gm % (H * W);
    int y  = rr / W, x = rr % W;
    const char* abase = A + ((size_t)(n * (H + 2) + y) * WP + x) * Ci + h * 32;
    const int xsw = (pl >> 1) & 3;
    const int wa0 = pl * 64 + (((2 * h) ^ xsw) << 4);
    const int wa1 = pl * 64 + (((2 * h + 1) ^ xsw) << 4);

    // ---- B staging role: 16B units, contiguous global, swizzled LDS ----
    const char* bbase = Bp + (size_t)bn * 128 * 64;
    int bdst[BU];
#pragma unroll
    for (int q = 0; q < BU; ++q) {
        int u = tid + q * T;
        int col = u >> 2, sl = u & 3;
        bdst[q] = col * 64 + ((sl ^ ((col >> 1) & 3)) << 4);
    }
    const size_t bstep = (size_t)Co * 64;

    // ---- fragment read offsets (swizzled) ----
    int raA[4];
#pragma unroll
    for (int i = 0; i < 4; ++i) {
        int row = wm * 64 + i * 16 + fr;
        raA[i] = row * 64 + ((fg ^ ((row >> 1) & 3)) << 4);
    }
    int raB[4];
#pragma unroll
    for (int j = 0; j < 4; ++j) {
        int col = wn * 64 + j * 16 + fr;
        raB[j] = col * 64 + ((fg ^ ((col >> 1) & 3)) << 4);
    }

    i32x4 acc[4][4] = {};

    // prologue: stage chunk 0
    {
        *reinterpret_cast<uint4*>(&lsA[0][wa0]) =
            *reinterpret_cast<const uint4*>(abase);
        *reinterpret_cast<uint4*>(&lsA[0][wa1]) =
            *reinterpret_cast<const uint4*>(abase + 16);
#pragma unroll
        for (int q = 0; q < BU; ++q)
            *reinterpret_cast<uint4*>(&lsB[0][bdst[q]]) =
                *reinterpret_cast<const uint4*>(bbase + (tid + q * T) * 16);
    }
    __syncthreads();

    for (int s = 0; s < S; ++s) {
        const int cur = s & 1;
        const bool more = (s + 1 < S);

        // prefetch next chunk into registers
        uint4 av0, av1, bst[BU];
        if (more) {
            int s1 = s + 1;
            int tap = s1 / KC, kc = s1 % KC;
            const char* src = abase + ((tap / 3) * WP + (tap % 3)) * Ci + kc * 64;
            av0 = *reinterpret_cast<const uint4*>(src);
            av1 = *reinterpret_cast<const uint4*>(src + 16);
            const char* bsrc = bbase + (size_t)s1 * bstep;
#pragma unroll
            for (int q = 0; q < BU; ++q)
                bst[q] = *reinterpret_cast<const uint4*>(bsrc + (tid + q * T) * 16);
        }

        // compute on current chunk
        i32x4 af[4], bf[4];
#pragma unroll
        for (int i = 0; i < 4; ++i)
            af[i] = *reinterpret_cast<const i32x4*>(&lsA[cur][raA[i]]);
#pragma unroll
        for (int j = 0; j < 4; ++j)
            bf[j] = *reinterpret_cast<const i32x4*>(&lsB[cur][raB[j]]);
#pragma unroll
        for (int i = 0; i < 4; ++i)
#pragma unroll
            for (int j = 0; j < 4; ++j)
                acc[i][j] = __builtin_amdgcn_mfma_i32_16x16x64_i8(
                    af[i], bf[j], acc[i][j], 0, 0, 0);

        if (more) {
            *reinterpret_cast<uint4*>(&lsA[cur ^ 1][wa0]) = av0;
            *reinterpret_cast<uint4*>(&lsA[cur ^ 1][wa1]) = av1;
#pragma unroll
            for (int q = 0; q < BU; ++q)
                *reinterpret_cast<uint4*>(&lsB[cur ^ 1][bdst[q]]) = bst[q];
        }
        __syncthreads();
    }

    // epilogue: frag row = i*16 + fg*4 + r, col = j*16 + fr (verified map)
#pragma unroll
    for (int i = 0; i < 4; ++i) {
#pragma unroll
        for (int r = 0; r < 4; ++r) {
            int p = bm * TM + wm * 64 + i * 16 + fg * 4 + r;
            int nn = p / (H * W);
            int r2 = p % (H * W);
            size_t crow = ((size_t)(nn * H + r2 / W) * W + r2 % W) * Co;
#pragma unroll
            for (int j = 0; j < 4; ++j) {
                int col = bn * 128 + wn * 64 + j * 16 + fr;
                Cc[crow + col] = (short)acc[i][j][r];
            }
        }
    }
}

// ---------------------------------------------------------------------------
// pool(optional 2x2) + BN + sign -> i8 +-1 padded NHWC for next layer
// ---------------------------------------------------------------------------
__global__ void pool_sign_kernel(const short* __restrict__ c,
                                 const float* __restrict__ g,
                                 const float* __restrict__ b,
                                 const float* __restrict__ m,
                                 const float* __restrict__ v,
                                 char* __restrict__ outp,
                                 int H, int W, int Ho, int Wo, int Co,
                                 int pool, int total)
{
    int idx = blockIdx.x * 256 + threadIdx.x;
    if (idx >= total) return;
    int co = idx % Co;
    int t  = idx / Co;
    int xo = t % Wo; t /= Wo;
    int yo = t % Ho;
    int n  = t / Ho;
    int best;
    if (pool) {
        int m00 = c[((size_t)((n * H + 2 * yo) * W + 2 * xo)) * Co + co];
        int m01 = c[((size_t)((n * H + 2 * yo) * W + 2 * xo + 1)) * Co + co];
        int m10 = c[((size_t)((n * H + 2 * yo + 1) * W + 2 * xo)) * Co + co];
        int m11 = c[((size_t)((n * H + 2 * yo + 1) * W + 2 * xo + 1)) * Co + co];
        best = max(max(m00, m01), max(m10, m11));
    } else {
        best = c[((size_t)((n * H + yo) * W + xo)) * Co + co];
    }
    float tt = ((float)best - m[co]) * (g[co] * rsqrtf(v[co] + EPS)) + b[co];
    outp[((size_t)(n * (Ho + 2) + yo + 1) * (Wo + 2) + xo + 1) * Co + co] =
        tt >= 0.f ? 1 : -1;
}

// ---------------------------------------------------------------------------
// final: pool 2x2 + BN + hardtanh -> fp32 NCHW h6[n][co][yo][xo] (4x4)
// ---------------------------------------------------------------------------
__global__ void pool6_ht_kernel(const short* __restrict__ c,
                                const float* __restrict__ g,
                                const float* __restrict__ b,
                                const float* __restrict__ m,
                                const float* __restrict__ v,
                                float* __restrict__ h6)
{
    int idx = blockIdx.x * 256 + threadIdx.x;
    if (idx >= 128 * 512 * 16) return;
    int xo = idx & 3;
    int yo = (idx >> 2) & 3;
    int t  = idx >> 4;
    int co = t % 512;
    int n  = t / 512;
    int m00 = c[((size_t)((n * 8 + 2 * yo) * 8 + 2 * xo)) * 512 + co];
    int m01 = c[((size_t)((n * 8 + 2 * yo) * 8 + 2 * xo + 1)) * 512 + co];
    int m10 = c[((size_t)((n * 8 + 2 * yo + 1) * 8 + 2 * xo)) * 512 + co];
    int m11 = c[((size_t)((n * 8 + 2 * yo + 1) * 8 + 2 * xo + 1)) * 512 + co];
    int best = max(max(m00, m01), max(m10, m11));
    float tt = ((float)best - m[co]) * (g[co] * rsqrtf(v[co] + EPS)) + b[co];
    tt = fminf(1.f, fmaxf(-1.f, tt));
    h6[((size_t)(n * 512 + co) * 4 + yo) * 4 + xo] = tt;
}

// ---------------------------------------------------------------------------
// classifier: logits = h @ w_lin.T (128 x 8192 x 10) then log_softmax
// ---------------------------------------------------------------------------
__global__ void classifier_kernel(const float* __restrict__ h,
                                  const float* __restrict__ wl,
                                  float* __restrict__ out)
{
    int n = blockIdx.x;
    int tid = threadIdx.x;
    float acc[10];
#pragma unroll
    for (int j = 0; j < 10; ++j) acc[j] = 0.f;
    for (int k = tid; k < 8192; k += 256) {
        float hv = h[n * 8192 + k];
#pragma unroll
        for (int j = 0; j < 10; ++j) acc[j] += hv * wl[j * 8192 + k];
    }
    __shared__ float sred[256];
    __shared__ float logit[10];
    for (int j = 0; j < 10; ++j) {
        sred[tid] = acc[j];
        __syncthreads();
        for (int s = 128; s > 0; s >>= 1) {
            if (tid < s) sred[tid] += sred[tid + s];
            __syncthreads();
        }
        if (tid == 0) logit[j] = sred[0];
        __syncthreads();
    }
    if (tid == 0) {
        float mx = logit[0];
#pragma unroll
        for (int j = 1; j < 10; ++j) mx = fmaxf(mx, logit[j]);
        float s = 0.f;
#pragma unroll
        for (int j = 0; j < 10; ++j) s += expf(logit[j] - mx);
        float lse = logf(s) + mx;
#pragma unroll
        for (int j = 0; j < 10; ++j) out[n * 10 + j] = logit[j] - lse;
    }
}

// ===========================================================================
extern "C" void kernel_launch(void* const* d_in, const int* in_sizes, int n_in,
                              void* d_out, int out_size, void* d_ws, size_t ws_size,
                              hipStream_t stream)
{
    const float* x    = (const float*)d_in[0];
    const float* w1   = (const float*)d_in[1];
    const float* w2   = (const float*)d_in[2];
    const float* w3   = (const float*)d_in[3];
    const float* w4   = (const float*)d_in[4];
    const float* w5   = (const float*)d_in[5];
    const float* w6   = (const float*)d_in[6];
    const float* bn_g[6], *bn_b[6], *bn_m[6], *bn_v[6];
    for (int i = 0; i < 6; ++i) {
        bn_g[i] = (const float*)d_in[7 + i * 4 + 0];
        bn_b[i] = (const float*)d_in[7 + i * 4 + 1];
        bn_m[i] = (const float*)d_in[7 + i * 4 + 2];
        bn_v[i] = (const float*)d_in[7 + i * 4 + 3];
    }
    const float* wlin = (const float*)d_in[31];
    float* out = (float*)d_out;

    // rotating activation/conv-out slots (R4-R9-verified liveness plan)
    const size_t A1 = (size_t)128 * 34 * 34 * 384;     // 56.8 MB
    const size_t A2 = (size_t)128 * 18 * 18 * 384;
    const size_t A3 = (size_t)128 * 18 * 18 * 768;
    const size_t A4 = (size_t)128 * 10 * 10 * 768;
    const size_t A5 = (size_t)128 * 10 * 10 * 1536;
    const size_t C2 = (size_t)131072 * 384 * 2;        // 100.7 MB
    const size_t C4 = (size_t)32768 * 768 * 2;         // 50.3 MB
    const size_t S0 = A1;                              // holds a1,c3,a4,c6
    const size_t S1 = C2;                              // holds c2,a3,c5,h6
    const size_t S2 = C4;                              // holds a2,c4,a5

    char* ws = (char*)d_ws;
    auto alloc = [&](size_t bytes) {
        char* p = ws;
        ws += (bytes + 255) & ~(size_t)255;
        return p;
    };
    char* s0 = (char*)alloc(S0);
    char* s1 = (char*)alloc(S1);
    char* s2 = (char*)alloc(S2);
    // B packs, padded by one chunk (branchless prefetch)
    char* bp2 = (char*)alloc((size_t)(9 * 6 + 1) * 384 * 64);
    char* bp3 = (char*)alloc((size_t)(9 * 6 + 1) * 768 * 64);
    char* bp4 = (char*)alloc((size_t)(9 * 12 + 1) * 768 * 64);
    char* bp5 = (char*)alloc((size_t)(9 * 12 + 1) * 1536 * 64);
    char* bp6 = (char*)alloc((size_t)(9 * 24 + 1) * 512 * 64);

    char*  a1 = s0;
    short* c2 = (short*)s1;
    char*  a2 = s2;
    short* c3 = (short*)s0;
    char*  a3 = s1;
    short* c4 = (short*)s2;
    char*  a4 = s0;
    short* c5 = (short*)s1;
    char*  a5 = s2;
    short* c6 = (short*)s0;
    float* h6 = (float*)s1;

    // B repacks
    {
        int t;
        t = 384 * 9 * 384;
        pack_bp_kernel<<<(t + 255) / 256, 256, 0, stream>>>(w2, bp2, 384, 384);
        t = 768 * 9 * 384;
        pack_bp_kernel<<<(t + 255) / 256, 256, 0, stream>>>(w3, bp3, 768, 384);
        t = 768 * 9 * 768;
        pack_bp_kernel<<<(t + 255) / 256, 256, 0, stream>>>(w4, bp4, 768, 768);
        t = 1536 * 9 * 768;
        pack_bp_kernel<<<(t + 255) / 256, 256, 0, stream>>>(w5, bp5, 1536, 768);
        t = 512 * 9 * 1536;
        pack_bp_kernel<<<(t + 255) / 256, 256, 0, stream>>>(w6, bp6, 512, 1536);
    }

    // block 1 -> a1 (padded i8)
    hipMemsetAsync(a1, 0, A1, stream);
    conv1_a1_kernel<<<128 * 32, 384, 0, stream>>>(
        x, w1, bn_g[0], bn_b[0], bn_m[0], bn_v[0], a1);

    // L2: 384->384 @32x32   TM=256: GM=512, GN=3 -> 1536 blocks of 512 thr
    gemm_lds_kernel<384, 384, 32, 32, 4, 3><<<512 * 3, 512, 0, stream>>>(a1, bp2, c2);
    hipMemsetAsync(a2, 0, A2, stream);
    {
        int total = 128 * 16 * 16 * 384;
        pool_sign_kernel<<<(total + 255) / 256, 256, 0, stream>>>(
            c2, bn_g[1], bn_b[1], bn_m[1], bn_v[1], a2, 32, 32, 16, 16, 384, 1, total);
    }
    // L3: 384->768 @16x16   TM=256: GM=128, GN=6 -> 768 blocks
    gemm_lds_kernel<384, 768, 16, 16, 4, 6><<<128 * 6, 512, 0, stream>>>(a2, bp3, c3);
    hipMemsetAsync(a3, 0, A3, stream);
    {
        int total = 128 * 16 * 16 * 768;
        pool_sign_kernel<<<(total + 255) / 256, 256, 0, stream>>>(
            c3, bn_g[2], bn_b[2], bn_m[2], bn_v[2], a3, 16, 16, 16, 16, 768, 0, total);
    }
    // L4: 768->768 @16x16   TM=256: GM=128, GN=6 -> 768 blocks
    gemm_lds_kernel<768, 768, 16, 16, 4, 6><<<128 * 6, 512, 0, stream>>>(a3, bp4, c4);
    hipMemsetAsync(a4, 0, A4, stream);
    {
        int total = 128 * 8 * 8 * 768;
        pool_sign_kernel<<<(total + 255) / 256, 256, 0, stream>>>(
            c4, bn_g[3], bn_b[3], bn_m[3], bn_v[3], a4, 16, 16, 8, 8, 768, 1, total);
    }
    // L5: 768->1536 @8x8    TM=128: GM=64, GN=12 -> 768 blocks of 256 thr
    gemm_lds_kernel<768, 1536, 8, 8, 2, 12><<<64 * 12, 256, 0, stream>>>(a4, bp5, c5);
    hipMemsetAsync(a5, 0, A5, stream);
    {
        int total = 128 * 8 * 8 * 1536;
        pool_sign_kernel<<<(total + 255) / 256, 256, 0, stream>>>(
            c5, bn_g[4], bn_b[4], bn_m[4], bn_v[4], a5, 8, 8, 8, 8, 1536, 0, total);
    }
    // L6: 1536->512 @8x8    TM=128: GM=64, GN=4 -> 256 blocks
    gemm_lds_kernel<1536, 512, 8, 8, 2, 4><<<64 * 4, 256, 0, stream>>>(a5, bp6, c6);
    {
        int total = 128 * 512 * 16;
        pool6_ht_kernel<<<(total + 255) / 256, 256, 0, stream>>>(
            c6, bn_g[5], bn_b[5], bn_m[5], bn_v[5], h6);
    }
    classifier_kernel<<<128, 256, 0, stream>>>(h6, wlin, out);
}

// Round 11
// 1078.400 us; speedup vs baseline: 1.3021x; 1.1002x over previous
//
#include <hip/hip_runtime.h>
#include <stdint.h>

#define EPS 1e-5f

typedef __attribute__((ext_vector_type(4))) int i32x4;

// ---------------------------------------------------------------------------
// conv1 v2 (R10): fp32 conv 3->384 + BN + sign -> i8 +-1 padded NHWC.
// R9 post-mortem: old conv1 re-loaded weights per thread (5.3 GB through L1,
// ~135us floor). Now: block = (image, 8-row quarter), 384 thr = one co each;
// 27 weights in VGPRs (loaded once), input tile in LDS read via same-address
// broadcast (conflict-free), x unroll-2 so CSE shares the sliding window.
// Output: direct i8 +-1 byte store into a1[n][y+1][x+1][co] (coalesced).
// ---------------------------------------------------------------------------
__global__ __launch_bounds__(384) void conv1_a1_kernel(
    const float* __restrict__ x,
    const float* __restrict__ w1,
    const float* __restrict__ g,
    const float* __restrict__ b,
    const float* __restrict__ m,
    const float* __restrict__ v,
    char* __restrict__ a1)
{
    const int bid = blockIdx.x;
    const int n = bid >> 2;
    const int q = bid & 3;          // rows 8q..8q+7
    const int tid = threadIdx.x;    // co

    __shared__ float xin[3][10][34];   // [ci][y0-1+yy][col-1]

    const int y0 = q * 8;
    for (int idx = tid; idx < 3 * 10 * 34; idx += 384) {
        int xx = idx % 34;
        int yy = (idx / 34) % 10;
        int ci = idx / 340;
        int gy = y0 - 1 + yy, gx = xx - 1;
        float val = 0.f;
        if (gy >= 0 && gy < 32 && gx >= 0 && gx < 32)
            val = x[((n * 3 + ci) * 32 + gy) * 32 + gx];
        xin[ci][yy][xx] = val;
    }

    float wr[27];
    {
        const float* wp = w1 + tid * 27;
#pragma unroll
        for (int i = 0; i < 27; ++i) wr[i] = wp[i];
    }
    const float scale = g[tid] * rsqrtf(v[tid] + EPS);
    const float mean = m[tid], beta = b[tid];
    __syncthreads();

    for (int yy = 0; yy < 8; ++yy) {
        const int gy = y0 + yy;
        char* orow = a1 + ((size_t)(n * 34 + gy + 1) * 34 + 1) * 384 + tid;
#pragma unroll
        for (int xp = 0; xp < 32; xp += 2) {
            float a0 = 0.f, a1v = 0.f;
#pragma unroll
            for (int ci = 0; ci < 3; ++ci)
#pragma unroll
                for (int dy = 0; dy < 3; ++dy) {
                    float c0 = xin[ci][yy + dy][xp];
                    float c1 = xin[ci][yy + dy][xp + 1];
                    float c2 = xin[ci][yy + dy][xp + 2];
                    float c3 = xin[ci][yy + dy][xp + 3];
                    const float* wrow = &wr[(ci * 3 + dy) * 3];
                    a0 += c0 * wrow[0] + c1 * wrow[1] + c2 * wrow[2];
                    a1v += c1 * wrow[0] + c2 * wrow[1] + c3 * wrow[2];
                }
            float t0 = (a0 - mean) * scale + beta;
            float t1 = (a1v - mean) * scale + beta;
            orow[(size_t)xp * 384] = (t0 >= 0.f) ? 1 : -1;
            orow[(size_t)(xp + 1) * 384] = (t1 >= 0.f) ? 1 : -1;
        }
    }
}

// ---------------------------------------------------------------------------
// B repack into fragment order: Bp[s][col][fg*16+t], s = tap*KC+kc,
// element = sign(w[col][ci=kc*64+fg*16+t][tap]).  Padded by one chunk for
// branchless prefetch.
// ---------------------------------------------------------------------------
__global__ void pack_bp_kernel(const float* __restrict__ w,
                               char* __restrict__ bp, int Co, int Ci)
{
    int KC = Ci >> 6;
    int idx = blockIdx.x * 256 + threadIdx.x;
    int total = Co * 9 * Ci;
    if (idx >= total) return;
    int t  = idx & 15;
    int fg = (idx >> 4) & 3;
    int co = (idx >> 6) % Co;
    int s  = idx / (Co * 64);
    int tap = s / KC, kc = s % KC;
    int ci = kc * 64 + fg * 16 + t;
    bp[idx] = (w[((size_t)co * Ci + ci) * 9 + tap] >= 0.f) ? 1 : -1;
}

// ---------------------------------------------------------------------------
// gemm_lds: double-buffered implicit-GEMM binary conv (i8 MFMA), A AND B
// staged through LDS (R9-verified: fixed the L1 vector-return BW bound).
// M-tile = WM*64, N-tile 128, K-step 64. Swizzle slot ^= (idx>>1)&3 on
// write AND read (R7-verified conflict-free). XCD-chunked 1D grid (R7).
// ---------------------------------------------------------------------------
template<int Ci, int Co, int H, int W, int WM, int GN>
__global__ __launch_bounds__(WM * 128, 4) void gemm_lds_kernel(
    const char* __restrict__ A,
    const char* __restrict__ Bp,
    short* __restrict__ Cc)
{
    constexpr int T   = WM * 128;
    constexpr int TM  = WM * 64;
    constexpr int KC  = Ci / 64;
    constexpr int S   = 9 * KC;
    constexpr int WP  = W + 2;
    constexpr int GM  = (128 * H * W) / TM;
    constexpr int BU  = 512 / T;

    __shared__ __align__(16) char lsA[2][TM * 64];
    __shared__ __align__(16) char lsB[2][128 * 64];

    const int id = blockIdx.x;
    const int xcd = id & 7;
    const int s0 = id >> 3;
    const int bm = xcd * (GM / 8) + s0 / GN;
    const int bn = s0 % GN;

    const int tid = threadIdx.x;
    const int lane = tid & 63;
    const int wave = tid >> 6;
    const int wm = wave >> 1, wn = wave & 1;
    const int fr = lane & 15, fg = lane >> 4;

    const int pl = tid >> 1, h = tid & 1;
    int gm = bm * TM + pl;
    int n  = gm / (H * W);
    int rr = gm % (H * W);
    int y  = rr / W, x = rr % W;
    const char* abase = A + ((size_t)(n * (H + 2) + y) * WP + x) * Ci + h * 32;
    const int xsw = (pl >> 1) & 3;
    const int wa0 = pl * 64 + (((2 * h) ^ xsw) << 4);
    const int wa1 = pl * 64 + (((2 * h + 1) ^ xsw) << 4);

    const char* bbase = Bp + (size_t)bn * 128 * 64;
    int bdst[BU];
#pragma unroll
    for (int q = 0; q < BU; ++q) {
        int u = tid + q * T;
        int col = u >> 2, sl = u & 3;
        bdst[q] = col * 64 + ((sl ^ ((col >> 1) & 3)) << 4);
    }
    const size_t bstep = (size_t)Co * 64;

    int raA[4];
#pragma unroll
    for (int i = 0; i < 4; ++i) {
        int row = wm * 64 + i * 16 + fr;
        raA[i] = row * 64 + ((fg ^ ((row >> 1) & 3)) << 4);
    }
    int raB[4];
#pragma unroll
    for (int j = 0; j < 4; ++j) {
        int col = wn * 64 + j * 16 + fr;
        raB[j] = col * 64 + ((fg ^ ((col >> 1) & 3)) << 4);
    }

    i32x4 acc[4][4] = {};

    {
        *reinterpret_cast<uint4*>(&lsA[0][wa0]) =
            *reinterpret_cast<const uint4*>(abase);
        *reinterpret_cast<uint4*>(&lsA[0][wa1]) =
            *reinterpret_cast<const uint4*>(abase + 16);
#pragma unroll
        for (int q = 0; q < BU; ++q)
            *reinterpret_cast<uint4*>(&lsB[0][bdst[q]]) =
                *reinterpret_cast<const uint4*>(bbase + (tid + q * T) * 16);
    }
    __syncthreads();

    for (int s = 0; s < S; ++s) {
        const int cur = s & 1;
        const bool more = (s + 1 < S);

        uint4 av0, av1, bst[BU];
        if (more) {
            int s1 = s + 1;
            int tap = s1 / KC, kc = s1 % KC;
            const char* src = abase + ((tap / 3) * WP + (tap % 3)) * Ci + kc * 64;
            av0 = *reinterpret_cast<const uint4*>(src);
            av1 = *reinterpret_cast<const uint4*>(src + 16);
            const char* bsrc = bbase + (size_t)s1 * bstep;
#pragma unroll
            for (int q = 0; q < BU; ++q)
                bst[q] = *reinterpret_cast<const uint4*>(bsrc + (tid + q * T) * 16);
        }

        i32x4 af[4], bf[4];
#pragma unroll
        for (int i = 0; i < 4; ++i)
            af[i] = *reinterpret_cast<const i32x4*>(&lsA[cur][raA[i]]);
#pragma unroll
        for (int j = 0; j < 4; ++j)
            bf[j] = *reinterpret_cast<const i32x4*>(&lsB[cur][raB[j]]);
#pragma unroll
        for (int i = 0; i < 4; ++i)
#pragma unroll
            for (int j = 0; j < 4; ++j)
                acc[i][j] = __builtin_amdgcn_mfma_i32_16x16x64_i8(
                    af[i], bf[j], acc[i][j], 0, 0, 0);

        if (more) {
            *reinterpret_cast<uint4*>(&lsA[cur ^ 1][wa0]) = av0;
            *reinterpret_cast<uint4*>(&lsA[cur ^ 1][wa1]) = av1;
#pragma unroll
            for (int q = 0; q < BU; ++q)
                *reinterpret_cast<uint4*>(&lsB[cur ^ 1][bdst[q]]) = bst[q];
        }
        __syncthreads();
    }

#pragma unroll
    for (int i = 0; i < 4; ++i) {
#pragma unroll
        for (int r = 0; r < 4; ++r) {
            int p = bm * TM + wm * 64 + i * 16 + fg * 4 + r;
            int nn = p / (H * W);
            int r2 = p % (H * W);
            size_t crow = ((size_t)(nn * H + r2 / W) * W + r2 % W) * Co;
#pragma unroll
            for (int j = 0; j < 4; ++j) {
                int col = bn * 128 + wn * 64 + j * 16 + fr;
                Cc[crow + col] = (short)acc[i][j][r];
            }
        }
    }
}

// ---------------------------------------------------------------------------
// pool(optional 2x2) + BN + sign -> i8 +-1 padded NHWC for next layer
// ---------------------------------------------------------------------------
__global__ void pool_sign_kernel(const short* __restrict__ c,
                                 const float* __restrict__ g,
                                 const float* __restrict__ b,
                                 const float* __restrict__ m,
                                 const float* __restrict__ v,
                                 char* __restrict__ outp,
                                 int H, int W, int Ho, int Wo, int Co,
                                 int pool, int total)
{
    int idx = blockIdx.x * 256 + threadIdx.x;
    if (idx >= total) return;
    int co = idx % Co;
    int t  = idx / Co;
    int xo = t % Wo; t /= Wo;
    int yo = t % Ho;
    int n  = t / Ho;
    int best;
    if (pool) {
        int m00 = c[((size_t)((n * H + 2 * yo) * W + 2 * xo)) * Co + co];
        int m01 = c[((size_t)((n * H + 2 * yo) * W + 2 * xo + 1)) * Co + co];
        int m10 = c[((size_t)((n * H + 2 * yo + 1) * W + 2 * xo)) * Co + co];
        int m11 = c[((size_t)((n * H + 2 * yo + 1) * W + 2 * xo + 1)) * Co + co];
        best = max(max(m00, m01), max(m10, m11));
    } else {
        best = c[((size_t)((n * H + yo) * W + xo)) * Co + co];
    }
    float tt = ((float)best - m[co]) * (g[co] * rsqrtf(v[co] + EPS)) + b[co];
    outp[((size_t)(n * (Ho + 2) + yo + 1) * (Wo + 2) + xo + 1) * Co + co] =
        tt >= 0.f ? 1 : -1;
}

// ---------------------------------------------------------------------------
// final: pool 2x2 + BN + hardtanh -> fp32 NCHW h6[n][co][yo][xo] (4x4)
// ---------------------------------------------------------------------------
__global__ void pool6_ht_kernel(const short* __restrict__ c,
                                const float* __restrict__ g,
                                const float* __restrict__ b,
                                const float* __restrict__ m,
                                const float* __restrict__ v,
                                float* __restrict__ h6)
{
    int idx = blockIdx.x * 256 + threadIdx.x;
    if (idx >= 128 * 512 * 16) return;
    int xo = idx & 3;
    int yo = (idx >> 2) & 3;
    int t  = idx >> 4;
    int co = t % 512;
    int n  = t / 512;
    int m00 = c[((size_t)((n * 8 + 2 * yo) * 8 + 2 * xo)) * 512 + co];
    int m01 = c[((size_t)((n * 8 + 2 * yo) * 8 + 2 * xo + 1)) * 512 + co];
    int m10 = c[((size_t)((n * 8 + 2 * yo + 1) * 8 + 2 * xo)) * 512 + co];
    int m11 = c[((size_t)((n * 8 + 2 * yo + 1) * 8 + 2 * xo + 1)) * 512 + co];
    int best = max(max(m00, m01), max(m10, m11));
    float tt = ((float)best - m[co]) * (g[co] * rsqrtf(v[co] + EPS)) + b[co];
    tt = fminf(1.f, fmaxf(-1.f, tt));
    h6[((size_t)(n * 512 + co) * 4 + yo) * 4 + xo] = tt;
}

// ---------------------------------------------------------------------------
// classifier: logits = h @ w_lin.T (128 x 8192 x 10) then log_softmax
// ---------------------------------------------------------------------------
__global__ void classifier_kernel(const float* __restrict__ h,
                                  const float* __restrict__ wl,
                                  float* __restrict__ out)
{
    int n = blockIdx.x;
    int tid = threadIdx.x;
    float acc[10];
#pragma unroll
    for (int j = 0; j < 10; ++j) acc[j] = 0.f;
    for (int k = tid; k < 8192; k += 256) {
        float hv = h[n * 8192 + k];
#pragma unroll
        for (int j = 0; j < 10; ++j) acc[j] += hv * wl[j * 8192 + k];
    }
    __shared__ float sred[256];
    __shared__ float logit[10];
    for (int j = 0; j < 10; ++j) {
        sred[tid] = acc[j];
        __syncthreads();
        for (int s = 128; s > 0; s >>= 1) {
            if (tid < s) sred[tid] += sred[tid + s];
            __syncthreads();
        }
        if (tid == 0) logit[j] = sred[0];
        __syncthreads();
    }
    if (tid == 0) {
        float mx = logit[0];
#pragma unroll
        for (int j = 1; j < 10; ++j) mx = fmaxf(mx, logit[j]);
        float s = 0.f;
#pragma unroll
        for (int j = 0; j < 10; ++j) s += expf(logit[j] - mx);
        float lse = logf(s) + mx;
#pragma unroll
        for (int j = 0; j < 10; ++j) out[n * 10 + j] = logit[j] - lse;
    }
}

// ===========================================================================
extern "C" void kernel_launch(void* const* d_in, const int* in_sizes, int n_in,
                              void* d_out, int out_size, void* d_ws, size_t ws_size,
                              hipStream_t stream)
{
    const float* x    = (const float*)d_in[0];
    const float* w1   = (const float*)d_in[1];
    const float* w2   = (const float*)d_in[2];
    const float* w3   = (const float*)d_in[3];
    const float* w4   = (const float*)d_in[4];
    const float* w5   = (const float*)d_in[5];
    const float* w6   = (const float*)d_in[6];
    const float* bn_g[6], *bn_b[6], *bn_m[6], *bn_v[6];
    for (int i = 0; i < 6; ++i) {
        bn_g[i] = (const float*)d_in[7 + i * 4 + 0];
        bn_b[i] = (const float*)d_in[7 + i * 4 + 1];
        bn_m[i] = (const float*)d_in[7 + i * 4 + 2];
        bn_v[i] = (const float*)d_in[7 + i * 4 + 3];
    }
    const float* wlin = (const float*)d_in[31];
    float* out = (float*)d_out;

    // rotating activation/conv-out slots (R4-R10-verified liveness plan)
    const size_t A1 = (size_t)128 * 34 * 34 * 384;     // 56.8 MB
    const size_t A2 = (size_t)128 * 18 * 18 * 384;
    const size_t A3 = (size_t)128 * 18 * 18 * 768;
    const size_t A4 = (size_t)128 * 10 * 10 * 768;
    const size_t A5 = (size_t)128 * 10 * 10 * 1536;
    const size_t C2 = (size_t)131072 * 384 * 2;        // 100.7 MB
    const size_t C4 = (size_t)32768 * 768 * 2;         // 50.3 MB
    const size_t S0 = A1;                              // holds a1,c3,a4,c6
    const size_t S1 = C2;                              // holds c2,a3,c5,h6
    const size_t S2 = C4;                              // holds a2,c4,a5

    char* ws = (char*)d_ws;
    auto alloc = [&](size_t bytes) {
        char* p = ws;
        ws += (bytes + 255) & ~(size_t)255;
        return p;
    };
    char* s0 = (char*)alloc(S0);
    char* s1 = (char*)alloc(S1);
    char* s2 = (char*)alloc(S2);
    // B packs, padded by one chunk (branchless prefetch)
    char* bp2 = (char*)alloc((size_t)(9 * 6 + 1) * 384 * 64);
    char* bp3 = (char*)alloc((size_t)(9 * 6 + 1) * 768 * 64);
    char* bp4 = (char*)alloc((size_t)(9 * 12 + 1) * 768 * 64);
    char* bp5 = (char*)alloc((size_t)(9 * 12 + 1) * 1536 * 64);
    char* bp6 = (char*)alloc((size_t)(9 * 24 + 1) * 512 * 64);

    char*  a1 = s0;
    short* c2 = (short*)s1;
    char*  a2 = s2;
    short* c3 = (short*)s0;
    char*  a3 = s1;
    short* c4 = (short*)s2;
    char*  a4 = s0;
    short* c5 = (short*)s1;
    char*  a5 = s2;
    short* c6 = (short*)s0;
    float* h6 = (float*)s1;

    // B repacks
    {
        int t;
        t = 384 * 9 * 384;
        pack_bp_kernel<<<(t + 255) / 256, 256, 0, stream>>>(w2, bp2, 384, 384);
        t = 768 * 9 * 384;
        pack_bp_kernel<<<(t + 255) / 256, 256, 0, stream>>>(w3, bp3, 768, 384);
        t = 768 * 9 * 768;
        pack_bp_kernel<<<(t + 255) / 256, 256, 0, stream>>>(w4, bp4, 768, 768);
        t = 1536 * 9 * 768;
        pack_bp_kernel<<<(t + 255) / 256, 256, 0, stream>>>(w5, bp5, 1536, 768);
        t = 512 * 9 * 1536;
        pack_bp_kernel<<<(t + 255) / 256, 256, 0, stream>>>(w6, bp6, 512, 1536);
    }

    // block 1 -> a1 (padded i8); borders zeroed by memset
    hipMemsetAsync(a1, 0, A1, stream);
    conv1_a1_kernel<<<128 * 4, 384, 0, stream>>>(
        x, w1, bn_g[0], bn_b[0], bn_m[0], bn_v[0], a1);

    // L2: 384->384 @32x32   TM=256: GM=512, GN=3
    gemm_lds_kernel<384, 384, 32, 32, 4, 3><<<512 * 3, 512, 0, stream>>>(a1, bp2, c2);
    hipMemsetAsync(a2, 0, A2, stream);
    {
        int total = 128 * 16 * 16 * 384;
        pool_sign_kernel<<<(total + 255) / 256, 256, 0, stream>>>(
            c2, bn_g[1], bn_b[1], bn_m[1], bn_v[1], a2, 32, 32, 16, 16, 384, 1, total);
    }
    // L3: 384->768 @16x16   TM=256: GM=128, GN=6
    gemm_lds_kernel<384, 768, 16, 16, 4, 6><<<128 * 6, 512, 0, stream>>>(a2, bp3, c3);
    hipMemsetAsync(a3, 0, A3, stream);
    {
        int total = 128 * 16 * 16 * 768;
        pool_sign_kernel<<<(total + 255) / 256, 256, 0, stream>>>(
            c3, bn_g[2], bn_b[2], bn_m[2], bn_v[2], a3, 16, 16, 16, 16, 768, 0, total);
    }
    // L4: 768->768 @16x16   TM=256: GM=128, GN=6
    gemm_lds_kernel<768, 768, 16, 16, 4, 6><<<128 * 6, 512, 0, stream>>>(a3, bp4, c4);
    hipMemsetAsync(a4, 0, A4, stream);
    {
        int total = 128 * 8 * 8 * 768;
        pool_sign_kernel<<<(total + 255) / 256, 256, 0, stream>>>(
            c4, bn_g[3], bn_b[3], bn_m[3], bn_v[3], a4, 16, 16, 8, 8, 768, 1, total);
    }
    // L5: 768->1536 @8x8    TM=128: GM=64, GN=12
    gemm_lds_kernel<768, 1536, 8, 8, 2, 12><<<64 * 12, 256, 0, stream>>>(a4, bp5, c5);
    hipMemsetAsync(a5, 0, A5, stream);
    {
        int total = 128 * 8 * 8 * 1536;
        pool_sign_kernel<<<(total + 255) / 256, 256, 0, stream>>>(
            c5, bn_g[4], bn_b[4], bn_m[4], bn_v[4], a5, 8, 8, 8, 8, 1536, 0, total);
    }
    // L6: 1536->512 @8x8    TM=128: GM=64, GN=4
    gemm_lds_kernel<1536, 512, 8, 8, 2, 4><<<64 * 4, 256, 0, stream>>>(a5, bp6, c6);
    {
        int total = 128 * 512 * 16;
        pool6_ht_kernel<<<(total + 255) / 256, 256, 0, stream>>>(
            c6, bn_g[5], bn_b[5], bn_m[5], bn_v[5], h6);
    }
    classifier_kernel<<<128, 256, 0, stream>>>(h6, wlin, out);
}

// Round 12
// 884.137 us; speedup vs baseline: 1.5882x; 1.2197x over previous
//
#include <hip/hip_runtime.h>
#include <stdint.h>

#define EPS 1e-5f

typedef __attribute__((ext_vector_type(4))) int i32x4;

// ---------------------------------------------------------------------------
// conv1 (R10-verified): fp32 conv 3->384 + BN + sign -> i8 +-1 padded NHWC.
// ---------------------------------------------------------------------------
__global__ __launch_bounds__(384) void conv1_a1_kernel(
    const float* __restrict__ x,
    const float* __restrict__ w1,
    const float* __restrict__ g,
    const float* __restrict__ b,
    const float* __restrict__ m,
    const float* __restrict__ v,
    char* __restrict__ a1)
{
    const int bid = blockIdx.x;
    const int n = bid >> 2;
    const int q = bid & 3;          // rows 8q..8q+7
    const int tid = threadIdx.x;    // co

    __shared__ float xin[3][10][34];

    const int y0 = q * 8;
    for (int idx = tid; idx < 3 * 10 * 34; idx += 384) {
        int xx = idx % 34;
        int yy = (idx / 34) % 10;
        int ci = idx / 340;
        int gy = y0 - 1 + yy, gx = xx - 1;
        float val = 0.f;
        if (gy >= 0 && gy < 32 && gx >= 0 && gx < 32)
            val = x[((n * 3 + ci) * 32 + gy) * 32 + gx];
        xin[ci][yy][xx] = val;
    }

    float wr[27];
    {
        const float* wp = w1 + tid * 27;
#pragma unroll
        for (int i = 0; i < 27; ++i) wr[i] = wp[i];
    }
    const float scale = g[tid] * rsqrtf(v[tid] + EPS);
    const float mean = m[tid], beta = b[tid];
    __syncthreads();

    for (int yy = 0; yy < 8; ++yy) {
        const int gy = y0 + yy;
        char* orow = a1 + ((size_t)(n * 34 + gy + 1) * 34 + 1) * 384 + tid;
#pragma unroll
        for (int xp = 0; xp < 32; xp += 2) {
            float a0 = 0.f, a1v = 0.f;
#pragma unroll
            for (int ci = 0; ci < 3; ++ci)
#pragma unroll
                for (int dy = 0; dy < 3; ++dy) {
                    float c0 = xin[ci][yy + dy][xp];
                    float c1 = xin[ci][yy + dy][xp + 1];
                    float c2 = xin[ci][yy + dy][xp + 2];
                    float c3 = xin[ci][yy + dy][xp + 3];
                    const float* wrow = &wr[(ci * 3 + dy) * 3];
                    a0 += c0 * wrow[0] + c1 * wrow[1] + c2 * wrow[2];
                    a1v += c1 * wrow[0] + c2 * wrow[1] + c3 * wrow[2];
                }
            float t0 = (a0 - mean) * scale + beta;
            float t1 = (a1v - mean) * scale + beta;
            orow[(size_t)xp * 384] = (t0 >= 0.f) ? 1 : -1;
            orow[(size_t)(xp + 1) * 384] = (t1 >= 0.f) ? 1 : -1;
        }
    }
}

// ---------------------------------------------------------------------------
// B repack into fragment order (R7-verified); padded by one chunk.
// ---------------------------------------------------------------------------
__global__ void pack_bp_kernel(const float* __restrict__ w,
                               char* __restrict__ bp, int Co, int Ci)
{
    int KC = Ci >> 6;
    int idx = blockIdx.x * 256 + threadIdx.x;
    int total = Co * 9 * Ci;
    if (idx >= total) return;
    int t  = idx & 15;
    int fg = (idx >> 4) & 3;
    int co = (idx >> 6) % Co;
    int s  = idx / (Co * 64);
    int tap = s / KC, kc = s % KC;
    int ci = kc * 64 + fg * 16 + t;
    bp[idx] = (w[((size_t)co * Ci + ci) * 9 + tap] >= 0.f) ? 1 : -1;
}

// ---------------------------------------------------------------------------
// gemm_fused (R11): R9's verified dbuf LDS GEMM + FUSED pool/BN/sign epilogue.
// Eliminates the i16 C buffers (100+50+50+25+8 MB HBM round-trips) and the
// pool_sign kernels. 2x2 maxpool is in-register given the fragment map
// (row = i*16 + fg*4 + r): horizontal partners = r-pairs (same lane);
// vertical partners: W=32 -> (i, i+2); W=16 -> (2iv, 2iv+1); W=8 -> lane^32
// (one __shfl_xor). Output: padded-NHWC i8 +-1 (or fp32 hardtanh NCHW, L6).
// K-loop/LDS/swizzle/XCD-chunking byte-identical to R9 (absmax-0 verified).
// ---------------------------------------------------------------------------
template<int Ci, int Co, int H, int W, int WM, int GN, bool POOL, bool OUTF32>
__global__ __launch_bounds__(WM * 128, 4) void gemm_fused_kernel(
    const char* __restrict__ A,
    const char* __restrict__ Bp,
    const float* __restrict__ g, const float* __restrict__ b,
    const float* __restrict__ m, const float* __restrict__ v,
    char* __restrict__ aout, float* __restrict__ fout)
{
    constexpr int T   = WM * 128;
    constexpr int TM  = WM * 64;
    constexpr int KC  = Ci / 64;
    constexpr int S   = 9 * KC;
    constexpr int WP  = W + 2;
    constexpr int GM  = (128 * H * W) / TM;
    constexpr int BU  = 512 / T;
    constexpr int HO  = POOL ? H / 2 : H;
    constexpr int WO  = POOL ? W / 2 : W;

    __shared__ __align__(16) char lsA[2][TM * 64];
    __shared__ __align__(16) char lsB[2][128 * 64];

    const int id = blockIdx.x;
    const int xcd = id & 7;
    const int s0 = id >> 3;
    const int bm = xcd * (GM / 8) + s0 / GN;
    const int bn = s0 % GN;

    const int tid = threadIdx.x;
    const int lane = tid & 63;
    const int wave = tid >> 6;
    const int wm = wave >> 1, wn = wave & 1;
    const int fr = lane & 15, fg = lane >> 4;

    const int pl = tid >> 1, h = tid & 1;
    int gm = bm * TM + pl;
    int n_  = gm / (H * W);
    int rr = gm % (H * W);
    int y_  = rr / W, x_ = rr % W;
    const char* abase = A + ((size_t)(n_ * (H + 2) + y_) * WP + x_) * Ci + h * 32;
    const int xsw = (pl >> 1) & 3;
    const int wa0 = pl * 64 + (((2 * h) ^ xsw) << 4);
    const int wa1 = pl * 64 + (((2 * h + 1) ^ xsw) << 4);

    const char* bbase = Bp + (size_t)bn * 128 * 64;
    int bdst[BU];
#pragma unroll
    for (int q = 0; q < BU; ++q) {
        int u = tid + q * T;
        int col = u >> 2, sl = u & 3;
        bdst[q] = col * 64 + ((sl ^ ((col >> 1) & 3)) << 4);
    }
    const size_t bstep = (size_t)Co * 64;

    int raA[4];
#pragma unroll
    for (int i = 0; i < 4; ++i) {
        int row = wm * 64 + i * 16 + fr;
        raA[i] = row * 64 + ((fg ^ ((row >> 1) & 3)) << 4);
    }
    int raB[4];
#pragma unroll
    for (int j = 0; j < 4; ++j) {
        int col = wn * 64 + j * 16 + fr;
        raB[j] = col * 64 + ((fg ^ ((col >> 1) & 3)) << 4);
    }

    i32x4 acc[4][4] = {};

    {
        *reinterpret_cast<uint4*>(&lsA[0][wa0]) =
            *reinterpret_cast<const uint4*>(abase);
        *reinterpret_cast<uint4*>(&lsA[0][wa1]) =
            *reinterpret_cast<const uint4*>(abase + 16);
#pragma unroll
        for (int q = 0; q < BU; ++q)
            *reinterpret_cast<uint4*>(&lsB[0][bdst[q]]) =
                *reinterpret_cast<const uint4*>(bbase + (tid + q * T) * 16);
    }
    __syncthreads();

    for (int s = 0; s < S; ++s) {
        const int cur = s & 1;
        const bool more = (s + 1 < S);

        uint4 av0, av1, bst[BU];
        if (more) {
            int s1 = s + 1;
            int tap = s1 / KC, kc = s1 % KC;
            const char* src = abase + ((tap / 3) * WP + (tap % 3)) * Ci + kc * 64;
            av0 = *reinterpret_cast<const uint4*>(src);
            av1 = *reinterpret_cast<const uint4*>(src + 16);
            const char* bsrc = bbase + (size_t)s1 * bstep;
#pragma unroll
            for (int q = 0; q < BU; ++q)
                bst[q] = *reinterpret_cast<const uint4*>(bsrc + (tid + q * T) * 16);
        }

        i32x4 af[4], bf[4];
#pragma unroll
        for (int i = 0; i < 4; ++i)
            af[i] = *reinterpret_cast<const i32x4*>(&lsA[cur][raA[i]]);
#pragma unroll
        for (int j = 0; j < 4; ++j)
            bf[j] = *reinterpret_cast<const i32x4*>(&lsB[cur][raB[j]]);
#pragma unroll
        for (int i = 0; i < 4; ++i)
#pragma unroll
            for (int j = 0; j < 4; ++j)
                acc[i][j] = __builtin_amdgcn_mfma_i32_16x16x64_i8(
                    af[i], bf[j], acc[i][j], 0, 0, 0);

        if (more) {
            *reinterpret_cast<uint4*>(&lsA[cur ^ 1][wa0]) = av0;
            *reinterpret_cast<uint4*>(&lsA[cur ^ 1][wa1]) = av1;
#pragma unroll
            for (int q = 0; q < BU; ++q)
                *reinterpret_cast<uint4*>(&lsB[cur ^ 1][bdst[q]]) = bst[q];
        }
        __syncthreads();
    }

    // ---------------- fused epilogue ----------------
    int colj[4];
    float sc[4], mn[4], bt[4];
#pragma unroll
    for (int j = 0; j < 4; ++j) {
        colj[j] = bn * 128 + wn * 64 + j * 16 + fr;
        sc[j] = g[colj[j]] * rsqrtf(v[colj[j]] + EPS);
        mn[j] = m[colj[j]];
        bt[j] = b[colj[j]];
    }

    if constexpr (POOL && W == 32) {
        // L2: n = bm/4; Y = 4*(bm%4)+wm; vertical pair (i, i+2); horiz r-pair
        const int n = bm >> 2;
        const int Y = 4 * (bm & 3) + wm;
#pragma unroll
        for (int ip = 0; ip < 2; ++ip)
#pragma unroll
            for (int rp = 0; rp < 2; ++rp) {
                int X = ip * 8 + fg * 2 + rp;
#pragma unroll
                for (int j = 0; j < 4; ++j) {
                    int val = max(max(acc[ip][j][2 * rp], acc[ip][j][2 * rp + 1]),
                                  max(acc[ip + 2][j][2 * rp], acc[ip + 2][j][2 * rp + 1]));
                    float t = ((float)val - mn[j]) * sc[j] + bt[j];
                    aout[((size_t)(n * (HO + 2) + Y + 1) * (WO + 2) + X + 1) * Co + colj[j]]
                        = (t >= 0.f) ? 1 : -1;
                }
            }
    } else if constexpr (POOL && W == 16) {
        // L4: n = bm; y = wm*4+i; vertical pair (2iv, 2iv+1); horiz r-pair
        const int n = bm;
#pragma unroll
        for (int iv = 0; iv < 2; ++iv) {
            int Y = wm * 2 + iv;
#pragma unroll
            for (int rp = 0; rp < 2; ++rp) {
                int X = fg * 2 + rp;
#pragma unroll
                for (int j = 0; j < 4; ++j) {
                    int val = max(max(acc[2 * iv][j][2 * rp], acc[2 * iv][j][2 * rp + 1]),
                                  max(acc[2 * iv + 1][j][2 * rp], acc[2 * iv + 1][j][2 * rp + 1]));
                    float t = ((float)val - mn[j]) * sc[j] + bt[j];
                    aout[((size_t)(n * (HO + 2) + Y + 1) * (WO + 2) + X + 1) * Co + colj[j]]
                        = (t >= 0.f) ? 1 : -1;
                }
            }
        }
    } else if constexpr (POOL && W == 8) {
        // L6 (OUTF32): n = bm*2+wm; y = 2i+(fg>>1); vertical partner = lane^32
        const int n = bm * 2 + wm;
#pragma unroll
        for (int i = 0; i < 4; ++i)
#pragma unroll
            for (int rp = 0; rp < 2; ++rp)
#pragma unroll
                for (int j = 0; j < 4; ++j) {
                    int hm = max(acc[i][j][2 * rp], acc[i][j][2 * rp + 1]);
                    int other = __shfl_xor(hm, 32);
                    int val = max(hm, other);
                    if (fg < 2) {
                        int X = (fg & 1) * 2 + rp;
                        float t = ((float)val - mn[j]) * sc[j] + bt[j];
                        t = fminf(1.f, fmaxf(-1.f, t));
                        fout[((size_t)(n * Co + colj[j]) * 4 + i) * 4 + X] = t;
                    }
                }
    } else if constexpr (!POOL && W == 16) {
        // L3: n = bm; y = wm*4 + i; x = fg*4 + r
        const int n = bm;
#pragma unroll
        for (int i = 0; i < 4; ++i) {
            int y = wm * 4 + i;
#pragma unroll
            for (int r = 0; r < 4; ++r) {
                int x = fg * 4 + r;
#pragma unroll
                for (int j = 0; j < 4; ++j) {
                    float t = ((float)acc[i][j][r] - mn[j]) * sc[j] + bt[j];
                    aout[((size_t)(n * (H + 2) + y + 1) * (W + 2) + x + 1) * Co + colj[j]]
                        = (t >= 0.f) ? 1 : -1;
                }
            }
        }
    } else {
        // L5 (!POOL, W==8): n = bm*2+wm; y = 2i+(fg>>1); x = (fg&1)*4+r
        const int n = bm * 2 + wm;
#pragma unroll
        for (int i = 0; i < 4; ++i) {
            int y = 2 * i + (fg >> 1);
#pragma unroll
            for (int r = 0; r < 4; ++r) {
                int x = (fg & 1) * 4 + r;
#pragma unroll
                for (int j = 0; j < 4; ++j) {
                    float t = ((float)acc[i][j][r] - mn[j]) * sc[j] + bt[j];
                    aout[((size_t)(n * (H + 2) + y + 1) * (W + 2) + x + 1) * Co + colj[j]]
                        = (t >= 0.f) ? 1 : -1;
                }
            }
        }
    }
}

// ---------------------------------------------------------------------------
// classifier: logits = h @ w_lin.T (128 x 8192 x 10) then log_softmax
// ---------------------------------------------------------------------------
__global__ void classifier_kernel(const float* __restrict__ h,
                                  const float* __restrict__ wl,
                                  float* __restrict__ out)
{
    int n = blockIdx.x;
    int tid = threadIdx.x;
    float acc[10];
#pragma unroll
    for (int j = 0; j < 10; ++j) acc[j] = 0.f;
    for (int k = tid; k < 8192; k += 256) {
        float hv = h[n * 8192 + k];
#pragma unroll
        for (int j = 0; j < 10; ++j) acc[j] += hv * wl[j * 8192 + k];
    }
    __shared__ float sred[256];
    __shared__ float logit[10];
    for (int j = 0; j < 10; ++j) {
        sred[tid] = acc[j];
        __syncthreads();
        for (int s = 128; s > 0; s >>= 1) {
            if (tid < s) sred[tid] += sred[tid + s];
            __syncthreads();
        }
        if (tid == 0) logit[j] = sred[0];
        __syncthreads();
    }
    if (tid == 0) {
        float mx = logit[0];
#pragma unroll
        for (int j = 1; j < 10; ++j) mx = fmaxf(mx, logit[j]);
        float s = 0.f;
#pragma unroll
        for (int j = 0; j < 10; ++j) s += expf(logit[j] - mx);
        float lse = logf(s) + mx;
#pragma unroll
        for (int j = 0; j < 10; ++j) out[n * 10 + j] = logit[j] - lse;
    }
}

// ===========================================================================
extern "C" void kernel_launch(void* const* d_in, const int* in_sizes, int n_in,
                              void* d_out, int out_size, void* d_ws, size_t ws_size,
                              hipStream_t stream)
{
    const float* x    = (const float*)d_in[0];
    const float* w1   = (const float*)d_in[1];
    const float* w2   = (const float*)d_in[2];
    const float* w3   = (const float*)d_in[3];
    const float* w4   = (const float*)d_in[4];
    const float* w5   = (const float*)d_in[5];
    const float* w6   = (const float*)d_in[6];
    const float* bn_g[6], *bn_b[6], *bn_m[6], *bn_v[6];
    for (int i = 0; i < 6; ++i) {
        bn_g[i] = (const float*)d_in[7 + i * 4 + 0];
        bn_b[i] = (const float*)d_in[7 + i * 4 + 1];
        bn_m[i] = (const float*)d_in[7 + i * 4 + 2];
        bn_v[i] = (const float*)d_in[7 + i * 4 + 3];
    }
    const float* wlin = (const float*)d_in[31];
    float* out = (float*)d_out;

    // activation slots (C buffers eliminated by fused epilogue, R11)
    const size_t A1 = (size_t)128 * 34 * 34 * 384;   // 56.8 MB (slot A)
    const size_t A2 = (size_t)128 * 18 * 18 * 384;   // 15.9 MB
    const size_t A3 = (size_t)128 * 18 * 18 * 768;   // 31.9 MB
    const size_t A4 = (size_t)128 * 10 * 10 * 768;   //  9.8 MB
    const size_t A5 = (size_t)128 * 10 * 10 * 1536;  // 19.7 MB
    const size_t SB = A2;                            // a2, a4 share
    const size_t SC = A3;                            // a3, a5 share
    const size_t H6 = (size_t)128 * 8192 * 4;

    char* ws = (char*)d_ws;
    auto alloc = [&](size_t bytes) {
        char* p = ws;
        ws += (bytes + 255) & ~(size_t)255;
        return p;
    };
    char*  a1 = (char*)alloc(A1);
    char*  sb = (char*)alloc(SB);
    char*  scs = (char*)alloc(SC);
    float* h6 = (float*)alloc(H6);
    char* bp2 = (char*)alloc((size_t)(9 * 6 + 1) * 384 * 64);
    char* bp3 = (char*)alloc((size_t)(9 * 6 + 1) * 768 * 64);
    char* bp4 = (char*)alloc((size_t)(9 * 12 + 1) * 768 * 64);
    char* bp5 = (char*)alloc((size_t)(9 * 12 + 1) * 1536 * 64);
    char* bp6 = (char*)alloc((size_t)(9 * 24 + 1) * 512 * 64);

    char* a2 = sb;
    char* a3 = scs;
    char* a4 = sb;
    char* a5 = scs;

    // B repacks
    {
        int t;
        t = 384 * 9 * 384;
        pack_bp_kernel<<<(t + 255) / 256, 256, 0, stream>>>(w2, bp2, 384, 384);
        t = 768 * 9 * 384;
        pack_bp_kernel<<<(t + 255) / 256, 256, 0, stream>>>(w3, bp3, 768, 384);
        t = 768 * 9 * 768;
        pack_bp_kernel<<<(t + 255) / 256, 256, 0, stream>>>(w4, bp4, 768, 768);
        t = 1536 * 9 * 768;
        pack_bp_kernel<<<(t + 255) / 256, 256, 0, stream>>>(w5, bp5, 1536, 768);
        t = 512 * 9 * 1536;
        pack_bp_kernel<<<(t + 255) / 256, 256, 0, stream>>>(w6, bp6, 512, 1536);
    }

    // block 1 -> a1 (padded i8)
    hipMemsetAsync(a1, 0, A1, stream);
    conv1_a1_kernel<<<128 * 4, 384, 0, stream>>>(
        x, w1, bn_g[0], bn_b[0], bn_m[0], bn_v[0], a1);

    // L2: 384->384 @32x32 +pool -> a2   (GM=512, GN=3)
    hipMemsetAsync(a2, 0, A2, stream);
    gemm_fused_kernel<384, 384, 32, 32, 4, 3, true, false>
        <<<512 * 3, 512, 0, stream>>>(a1, bp2, bn_g[1], bn_b[1], bn_m[1], bn_v[1],
                                      a2, nullptr);
    // L3: 384->768 @16x16 -> a3         (GM=128, GN=6)
    hipMemsetAsync(a3, 0, A3, stream);
    gemm_fused_kernel<384, 768, 16, 16, 4, 6, false, false>
        <<<128 * 6, 512, 0, stream>>>(a2, bp3, bn_g[2], bn_b[2], bn_m[2], bn_v[2],
                                      a3, nullptr);
    // L4: 768->768 @16x16 +pool -> a4   (GM=128, GN=6)
    hipMemsetAsync(a4, 0, A4, stream);
    gemm_fused_kernel<768, 768, 16, 16, 4, 6, true, false>
        <<<128 * 6, 512, 0, stream>>>(a3, bp4, bn_g[3], bn_b[3], bn_m[3], bn_v[3],
                                      a4, nullptr);
    // L5: 768->1536 @8x8 -> a5          (GM=64, GN=12)
    hipMemsetAsync(a5, 0, A5, stream);
    gemm_fused_kernel<768, 1536, 8, 8, 2, 12, false, false>
        <<<64 * 12, 256, 0, stream>>>(a4, bp5, bn_g[4], bn_b[4], bn_m[4], bn_v[4],
                                      a5, nullptr);
    // L6: 1536->512 @8x8 +pool -> h6 fp32 NCHW (GM=64, GN=4)
    gemm_fused_kernel<1536, 512, 8, 8, 2, 4, true, true>
        <<<64 * 4, 256, 0, stream>>>(a5, bp6, bn_g[5], bn_b[5], bn_m[5], bn_v[5],
                                     nullptr, h6);

    classifier_kernel<<<128, 256, 0, stream>>>(h6, wlin, out);
}